// Round 7
// baseline (262.541 us; speedup 1.0000x reference)
//
#include <hip/hip_runtime.h>
#include <cmath>

// GNNCASimple: x:[N,128] -> enc MLP -> h:[N,256] -> msg GEMM -> m:[N,256]
// -> segment_sum over E edges -> aggr:[N,256] -> dec(cat(aggr,h)) -> out:[N,128]
// N=50000, E=400000, D=128, H=256, steps=1.
//
// R13: 234.6 best. R14-R16: barrier/LDS/conflict variants all NEUTRAL.
// R17/R18: persistence bug (dec seam) -> FAILED. R19 bisect: enc-persistent
//      PASSES (~53us, total 248.8); dec-persistence was the bug.
// KEY INFERENCE (R19): persistent enc (forced 1 block/CU) == non-persistent
//      enc timing => effective residency was ALWAYS ~1 block/CU (occupancy
//      stuck at 28% = 8-9 waves/CU in every round). All pipes <15% busy is
//      what 8 waves/CU of exposed latency looks like. The wave SUPPLY, not
//      the in-block schedule, is the bound.
// R20: 1024-thread blocks (16 waves), 128-row tiles, grid 391. Wave grid
//      2x8 (row-half x col-slice). Per-wave inner loops = R16's known-good
//      streamed-B form (VGPR ~60 << 128 budget @ 4 waves/SIMD). LDS 64KB
//      per block (x aliased into hL[4..7]; dec As aliased into dL[0..3],
//      16 stage slots == 16 waves). If 1-block/CU holds: occupancy -> ~50%,
//      enc/dec ~0.6x. If occupancy stays 28%: cap is wave-slots/CU, in-kernel
//      levers exhausted.

typedef __attribute__((ext_vector_type(8))) short  short8;   // 8 bf16 (4 VGPR)
typedef __attribute__((ext_vector_type(4))) float  f32x4;    // MFMA acc
typedef __attribute__((ext_vector_type(4))) unsigned short us4;

typedef unsigned short u16;
typedef unsigned int   u32;

static __device__ __forceinline__ u16 f2bf(float f) {
    u32 u = __float_as_uint(f);
    u = (u + 0x7FFFu + ((u >> 16) & 1u)) >> 16;   // round-to-nearest-even
    return (u16)u;
}
static __device__ __forceinline__ float bf2f(u16 h) {
    return __uint_as_float(((u32)h) << 16);
}

// async 16B global -> LDS; lds base wave-uniform (+ lane*16 implicit).
static __device__ __forceinline__ void g2l16(const void* g, void* l) {
    __builtin_amdgcn_global_load_lds(
        (const __attribute__((address_space(1))) u32*)g,
        (__attribute__((address_space(3))) u32*)l, 16, 0, 0);
}

// ---------------- fused encoder: x -> h, m (1024 thr, 128-row tile) --------
// 16 waves: rh = wave>>3 (row half, 64 rows), wcw = wave&7 (col slice, 32).
// hL[c][g][512]: k-chunk c (32 k), 16-row granule g (0..7), MFMA
// fragment-major (lane reads [lane*16,+16) -- conflict-free).
// x tile (128x128 bf16 = 32KB) aliases hL[4..7]; freed by the post-phase-1
// barrier before epilogue-1 overwrites. B streamed global->reg (R16 form).
__global__ __launch_bounds__(1024, 4) void enc_fused(
    const float* __restrict__ x, const u16* __restrict__ w1,
    const float* __restrict__ b1, const u16* __restrict__ w2,
    const float* __restrict__ b2, const u16* __restrict__ wm,
    const float* __restrict__ bm, u16* __restrict__ hout,
    u16* __restrict__ mout, const int N)
{
    __shared__ u16 hL[8][8][512];   // 64KB

    const int t    = threadIdx.x;
    const int r0   = blockIdx.x * 128;
    const int wave = t >> 6;          // 0..15
    const int lane = t & 63;
    const int n    = lane & 15;
    const int q    = lane >> 4;
    const int rh   = wave >> 3;       // row half
    const int wcw  = wave & 7;        // col slice
    const int wc   = wcw * 32;
    const int g0   = rh * 4;          // granule base for this wave's rows

    // ---- stage x tile: 128x128 fp32 -> bf16 fragment-major in hL[4..7] ----
#pragma unroll
    for (int kk = 0; kk < 4; kk++) {
        const int row = (t >> 5) + kk * 32;
        const int col = (t & 31) * 4;
        const int gr  = min(r0 + row, N - 1);
        const float4 v = *reinterpret_cast<const float4*>(
            x + (size_t)gr * 128 + col);
        us4 o = { f2bf(v.x), f2bf(v.y), f2bf(v.z), f2bf(v.w) };
        const int idx = (((col >> 3) & 3) * 16 + (row & 15)) * 8 + (col & 7);
        *reinterpret_cast<us4*>(&hL[4 + (col >> 5)][row >> 4][idx]) = o;
    }

    f32x4 acc[4][2];
#pragma unroll
    for (int i = 0; i < 4; i++)
#pragma unroll
        for (int j = 0; j < 2; j++) acc[i][j] = (f32x4)0.0f;

    // P1 B fragments (w1: [256 out][128 K]) -- all 4 K-steps up front
    short8 bp[4][2];
#pragma unroll
    for (int c = 0; c < 4; c++)
#pragma unroll
        for (int j = 0; j < 2; j++)
            bp[c][j] = *reinterpret_cast<const short8*>(
                w1 + (size_t)(wc + j * 16 + n) * 128 + c * 32 + q * 8);

    __syncthreads();   // x tile visible

    // ---- phase 1: K=128, no barriers inside ----
#pragma unroll
    for (int c = 0; c < 4; c++) {
        short8 af[4];
#pragma unroll
        for (int i = 0; i < 4; i++)
            af[i] = *reinterpret_cast<const short8*>(
                &hL[4 + c][g0 + i][lane * 8]);
#pragma unroll
        for (int i = 0; i < 4; i++)
#pragma unroll
            for (int j = 0; j < 2; j++)
                acc[i][j] = __builtin_amdgcn_mfma_f32_16x16x32_bf16(
                    af[i], bp[c][j], acc[i][j], 0, 0, 0);
    }

    // preload P2 B (w2: [256][256]), steps 0..3
#pragma unroll
    for (int c = 0; c < 4; c++)
#pragma unroll
        for (int j = 0; j < 2; j++)
            bp[c][j] = *reinterpret_cast<const short8*>(
                w2 + (size_t)(wc + j * 16 + n) * 256 + c * 32 + q * 8);

    __syncthreads();   // all phase-1 A reads done: hL[4..7] reusable

    {   // epilogue 1 -> hL[wcw][g0..g0+3], fragment-major
        const float bv0 = b1[wc + n];
        const float bv1 = b1[wc + 16 + n];
        const int np = q * 4;
#pragma unroll
        for (int i = 0; i < 4; i++)
#pragma unroll
            for (int reg = 0; reg < 4; reg++) {
#pragma unroll
                for (int j = 0; j < 2; j++) {
                    const float v = fmaxf(acc[i][j][reg] + (j ? bv1 : bv0), 0.0f);
                    const int q2 = j * 2 + (n >> 3);
                    hL[wcw][g0 + i][(q2 * 16 + np + reg) * 8 + (n & 7)] = f2bf(v);
                }
            }
    }
    __syncthreads();   // hL (h1) visible

    // ---- phase 2: K=256 from hL, rotating B prefetch ----
#pragma unroll
    for (int i = 0; i < 4; i++)
#pragma unroll
        for (int j = 0; j < 2; j++) acc[i][j] = (f32x4)0.0f;
#pragma unroll
    for (int c = 0; c < 8; c++) {
        short8 af[4];
#pragma unroll
        for (int i = 0; i < 4; i++)
            af[i] = *reinterpret_cast<const short8*>(&hL[c][g0 + i][lane * 8]);
#pragma unroll
        for (int i = 0; i < 4; i++)
#pragma unroll
            for (int j = 0; j < 2; j++)
                acc[i][j] = __builtin_amdgcn_mfma_f32_16x16x32_bf16(
                    af[i], bp[c & 3][j], acc[i][j], 0, 0, 0);
        if (c < 4) {   // prefetch step c+4 into the just-freed slot
#pragma unroll
            for (int j = 0; j < 2; j++)
                bp[c][j] = *reinterpret_cast<const short8*>(
                    w2 + (size_t)(wc + j * 16 + n) * 256 + (c + 4) * 32 + q * 8);
        }
    }

    // preload P3 B (wm: [256][256])
#pragma unroll
    for (int c = 0; c < 4; c++)
#pragma unroll
        for (int j = 0; j < 2; j++)
            bp[c][j] = *reinterpret_cast<const short8*>(
                wm + (size_t)(wc + j * 16 + n) * 256 + c * 32 + q * 8);

    {   // epilogue 2: h -> global, then rewrite hL
        const float bv0 = b2[wc + n];
        const float bv1 = b2[wc + 16 + n];
        const int np = q * 4;
#pragma unroll
        for (int i = 0; i < 4; i++)
#pragma unroll
            for (int reg = 0; reg < 4; reg++) {
                const int row = r0 + rh * 64 + i * 16 + q * 4 + reg;
                if (row < N) {
                    hout[(size_t)row * 256 + wc + n] =
                        f2bf(fmaxf(acc[i][0][reg] + bv0, 0.0f));
                    hout[(size_t)row * 256 + wc + 16 + n] =
                        f2bf(fmaxf(acc[i][1][reg] + bv1, 0.0f));
                }
            }
        __syncthreads();   // all waves done reading hL (phase 2)
#pragma unroll
        for (int i = 0; i < 4; i++)
#pragma unroll
            for (int reg = 0; reg < 4; reg++) {
#pragma unroll
                for (int j = 0; j < 2; j++) {
                    const float v = fmaxf(acc[i][j][reg] + (j ? bv1 : bv0), 0.0f);
                    const int q2 = j * 2 + (n >> 3);
                    hL[wcw][g0 + i][(q2 * 16 + np + reg) * 8 + (n & 7)] = f2bf(v);
                }
            }
    }
    __syncthreads();   // hL (h) visible

    // ---- phase 3: m = h Wm^T + bm (bp rotating) ----
#pragma unroll
    for (int i = 0; i < 4; i++)
#pragma unroll
        for (int j = 0; j < 2; j++) acc[i][j] = (f32x4)0.0f;
#pragma unroll
    for (int c = 0; c < 8; c++) {
        short8 af[4];
#pragma unroll
        for (int i = 0; i < 4; i++)
            af[i] = *reinterpret_cast<const short8*>(&hL[c][g0 + i][lane * 8]);
#pragma unroll
        for (int i = 0; i < 4; i++)
#pragma unroll
            for (int j = 0; j < 2; j++)
                acc[i][j] = __builtin_amdgcn_mfma_f32_16x16x32_bf16(
                    af[i], bp[c & 3][j], acc[i][j], 0, 0, 0);
        if (c < 4) {
#pragma unroll
            for (int j = 0; j < 2; j++)
                bp[c][j] = *reinterpret_cast<const short8*>(
                    wm + (size_t)(wc + j * 16 + n) * 256 + (c + 4) * 32 + q * 8);
        }
    }
    {   // epilogue 3: m -> global
        const float bv0 = bm[wc + n];
        const float bv1 = bm[wc + 16 + n];
#pragma unroll
        for (int i = 0; i < 4; i++)
#pragma unroll
            for (int reg = 0; reg < 4; reg++) {
                const int row = r0 + rh * 64 + i * 16 + q * 4 + reg;
                if (row < N) {
                    mout[(size_t)row * 256 + wc + n] =
                        f2bf(acc[i][0][reg] + bv0);
                    mout[(size_t)row * 256 + wc + 16 + n] =
                        f2bf(acc[i][1][reg] + bv1);
                }
            }
    }
}

// ---------------- fused decoder: aggr,h -> out (1024 thr, 128-row tile) ----
// Phase A: K=512. A staged per K-pair via g2l16 into dL[0..3] (alias),
// fragment-major via pre-swizzled global source; 16 (chunk,granule) slots
// per pair == 16 waves, one g2l16 each. B (wd1) streams global->reg.
// Phase B: out 128x128, K=256 from dL; wave = (row-half, 16 cols).
__global__ __launch_bounds__(1024, 4) void dec_fused(
    const u16* __restrict__ aggr, const u16* __restrict__ h,
    const u16* __restrict__ wd1, const float* __restrict__ bd1,
    const u16* __restrict__ wd2, const float* __restrict__ bd2,
    float* __restrict__ out, const int N)
{
    __shared__ u16 dL[8][8][512];   // 64KB; dL[0..3] doubles as As[2][2]

    const int t    = threadIdx.x;
    const int r0   = blockIdx.x * 128;
    const int wave = t >> 6;          // 0..15
    const int lane = t & 63;
    const int n    = lane & 15;
    const int q    = lane >> 4;
    const int rh   = wave >> 3;
    const int wcw  = wave & 7;
    const int wc   = wcw * 32;
    const int g0   = rh * 4;

    // A staging: wave stages granule w8 = wave&7 of chunk c = 2p + sub
    // (sub = wave>>3). Source swizzle: lane L fetches row (L&15),
    // k-group (L>>4) -> lands at LDS offset L*16 (fragment-major).
    const int sub  = wave >> 3;
    const int w8   = wave & 7;
    const int srow = min(r0 + w8 * 16 + (lane & 15), N - 1);
    const int kq8  = (lane >> 4) * 8;
    const u16* aptr = aggr + (size_t)srow * 256 + kq8;
    const u16* hptr = h    + (size_t)srow * 256 + kq8;

#define DEC_STAGE(p, buf)                                                   \
    {                                                                       \
        const int c_  = 2 * (p) + sub;                                      \
        const int kc_ = c_ * 32;                                            \
        const u16* sp_ = (kc_ < 256) ? (aptr + kc_) : (hptr + (kc_ - 256)); \
        g2l16(sp_, &dL[(buf) * 2 + sub][w8][0]);                            \
    }

    f32x4 acc[4][2];
#pragma unroll
    for (int i = 0; i < 4; i++)
#pragma unroll
        for (int j = 0; j < 2; j++) acc[i][j] = (f32x4)0.0f;

    DEC_STAGE(0, 0);
    // preload B (wd1: [256 out][512 K]) steps 0..3
    short8 bp[4][2];
#pragma unroll
    for (int c = 0; c < 4; c++)
#pragma unroll
        for (int j = 0; j < 2; j++)
            bp[c][j] = *reinterpret_cast<const short8*>(
                wd1 + (size_t)(wc + j * 16 + n) * 512 + c * 32 + q * 8);
    __syncthreads();   // pair 0 staged

    // ---- phase A: 8 K-pairs (K=512) ----
#pragma unroll
    for (int p = 0; p < 8; p++) {
        if (p < 7) DEC_STAGE(p + 1, (p + 1) & 1);   // overlap with compute
#pragma unroll
        for (int s = 0; s < 2; s++) {
            const int c = 2 * p + s;
            short8 af[4];
#pragma unroll
            for (int i = 0; i < 4; i++)
                af[i] = *reinterpret_cast<const short8*>(
                    &dL[(p & 1) * 2 + s][g0 + i][lane * 8]);
#pragma unroll
            for (int i = 0; i < 4; i++)
#pragma unroll
                for (int j = 0; j < 2; j++)
                    acc[i][j] = __builtin_amdgcn_mfma_f32_16x16x32_bf16(
                        af[i], bp[c & 3][j], acc[i][j], 0, 0, 0);
            if (c + 4 < 16) {
#pragma unroll
                for (int j = 0; j < 2; j++)
                    bp[c & 3][j] = *reinterpret_cast<const short8*>(
                        wd1 + (size_t)(wc + j * 16 + n) * 512 +
                        (c + 4) * 32 + q * 8);
            }
        }
        __syncthreads();   // next pair staged; reads of this pair done
    }
#undef DEC_STAGE

    {   // epilogue A -> dL[wcw][g0..g0+3], fragment-major
        const float bv0 = bd1[wc + n];
        const float bv1 = bd1[wc + 16 + n];
        const int np = q * 4;
#pragma unroll
        for (int i = 0; i < 4; i++)
#pragma unroll
            for (int reg = 0; reg < 4; reg++) {
#pragma unroll
                for (int j = 0; j < 2; j++) {
                    const float v = fmaxf(acc[i][j][reg] + (j ? bv1 : bv0), 0.0f);
                    const int q2 = j * 2 + (n >> 3);
                    dL[wcw][g0 + i][(q2 * 16 + np + reg) * 8 + (n & 7)] = f2bf(v);
                }
            }
    }

    // preload phase-B B (wd2: [128 out][256 K]); wave covers 16 out cols
    const int wc2 = wcw * 16;
    short8 b2p[4];
#pragma unroll
    for (int c = 0; c < 4; c++)
        b2p[c] = *reinterpret_cast<const short8*>(
            wd2 + (size_t)(wc2 + n) * 256 + c * 32 + q * 8);
    __syncthreads();   // dL visible

    // ---- phase B: out 128x128, K=256 from dL ----
    f32x4 acc2[4];
#pragma unroll
    for (int i = 0; i < 4; i++) acc2[i] = (f32x4)0.0f;
#pragma unroll
    for (int c = 0; c < 8; c++) {
        short8 af[4], bf;
#pragma unroll
        for (int i = 0; i < 4; i++)
            af[i] = *reinterpret_cast<const short8*>(&dL[c][g0 + i][lane * 8]);
        bf = b2p[c & 3];
#pragma unroll
        for (int i = 0; i < 4; i++)
            acc2[i] = __builtin_amdgcn_mfma_f32_16x16x32_bf16(
                af[i], bf, acc2[i], 0, 0, 0);
        if (c < 4)
            b2p[c] = *reinterpret_cast<const short8*>(
                wd2 + (size_t)(wc2 + n) * 256 + (c + 4) * 32 + q * 8);
    }
    {
        const float bv = bd2[wc2 + n];
#pragma unroll
        for (int i = 0; i < 4; i++)
#pragma unroll
            for (int reg = 0; reg < 4; reg++) {
                const int row = r0 + rh * 64 + i * 16 + q * 4 + reg;
                if (row < N)
                    out[(size_t)row * 128 + wc2 + n] = tanhf(acc2[i][reg] + bv);
            }
    }
}

// ---------------- weight converts + cursor zero (one dispatch) -------------
__global__ __launch_bounds__(256) void cvt6_kernel(
    const float* s0, const float* s1, const float* s2, const float* s3,
    const float* s4,
    u16* d0, u16* d1, u16* d2, u16* d3, u16* d4,
    int* __restrict__ zp,
    int n0, int n1, int n2, int n3, int n4, int nz)
{
    const int i = blockIdx.x * 256 + threadIdx.x;
    if (blockIdx.y == 5) {
        if (i < nz) zp[i] = 0;
        return;
    }
    const float* s; u16* d; int nq;
    switch (blockIdx.y) {
        case 0: s = s0; d = d0; nq = n0; break;
        case 1: s = s1; d = d1; nq = n1; break;
        case 2: s = s2; d = d2; nq = n2; break;
        case 3: s = s3; d = d3; nq = n3; break;
        default: s = s4; d = d4; nq = n4; break;
    }
    if (i < nq) {
        const float4 v = reinterpret_cast<const float4*>(s)[i];
        us4 o = { f2bf(v.x), f2bf(v.y), f2bf(v.z), f2bf(v.w) };
        reinterpret_cast<us4*>(d)[i] = o;
    }
}

// ---------------- scan-free bucket fill ----------------
// Fixed capacity 64 slots/node; deg ~ Poisson(8) => overflow prob ~1e-34.
__global__ __launch_bounds__(256) void fill_kernel(
    const int* __restrict__ ei, int* __restrict__ cursor,
    int* __restrict__ bucket, const int E, const int Nn)
{
    const int e = blockIdx.x * 256 + threadIdx.x;
    if (e < E) {
        const int src = ei[e];
        const int dst = ei[(size_t)E + e];
        if ((unsigned)dst < (unsigned)Nn) {
            const int pos = atomicAdd(&cursor[dst], 1);
            if (pos < 64) bucket[(size_t)dst * 64 + pos] = src;
        }
    }
}

// ---------------- gather-sum (one wave per node, unroll-8) ----------------
__global__ __launch_bounds__(256) void gather_sum_kernel(
    const u16* __restrict__ m, const int* __restrict__ bucket,
    const int* __restrict__ cursor, u16* __restrict__ outa, const int Nn)
{
    const int wave = (int)((blockIdx.x * 256u + threadIdx.x) >> 6);
    const int lane = threadIdx.x & 63;
    if (wave >= Nn) return;
    const int cnt = min(cursor[wave], 64);
    const int* bl = bucket + (size_t)wave * 64;
    float a0 = 0.f, a1 = 0.f, a2 = 0.f, a3 = 0.f;
    for (int base = 0; base < cnt; base += 8) {
        int sidx[8];
#pragma unroll
        for (int u = 0; u < 8; u++)
            sidx[u] = (base + u < cnt) ? bl[base + u] : -1;
        us4 v[8];
#pragma unroll
        for (int u = 0; u < 8; u++) {
            const int s = ((unsigned)sidx[u] < (unsigned)Nn) ? sidx[u] : 0;
            v[u] = *reinterpret_cast<const us4*>(&m[(size_t)s * 256 + lane * 4]);
        }
#pragma unroll
        for (int u = 0; u < 8; u++) {
            if ((unsigned)sidx[u] < (unsigned)Nn) {
                a0 += bf2f(v[u].x); a1 += bf2f(v[u].y);
                a2 += bf2f(v[u].z); a3 += bf2f(v[u].w);
            }
        }
    }
    us4 o = { f2bf(a0), f2bf(a1), f2bf(a2), f2bf(a3) };
    *reinterpret_cast<us4*>(&outa[(size_t)wave * 256 + lane * 4]) = o;
}

extern "C" void kernel_launch(void* const* d_in, const int* in_sizes, int n_in,
                              void* d_out, int out_size, void* d_ws, size_t ws_size,
                              hipStream_t stream)
{
    const float* x      = (const float*)d_in[0];
    const int*   ei     = (const int*)d_in[1];   // [2][E]
    const float* enc_w1 = (const float*)d_in[3];
    const float* enc_b1 = (const float*)d_in[4];
    const float* enc_w2 = (const float*)d_in[5];
    const float* enc_b2 = (const float*)d_in[6];
    const float* msg_w  = (const float*)d_in[7];
    const float* msg_b  = (const float*)d_in[8];
    const float* dec_w1 = (const float*)d_in[9];
    const float* dec_b1 = (const float*)d_in[10];
    const float* dec_w2 = (const float*)d_in[11];
    const float* dec_b2 = (const float*)d_in[12];

    const int N = 50000, D = 128, H = 256;
    const int E = in_sizes[1] / 2;

    // ws layout: u16 slabs then int bucket CSR.
    u16* h    = (u16*)d_ws;                  // [N,256]
    u16* m    = h    + (size_t)N * H;        // [N,256]
    u16* aggr = m    + (size_t)N * H;        // [N,256]
    u16* w1   = aggr + (size_t)N * H;        // 256*128
    u16* w2   = w1 + 256 * 128;              // 256*256
    u16* wm   = w2 + 256 * 256;              // 256*256
    u16* wd1  = wm + 256 * 256;              // 256*512
    u16* wd2  = wd1 + 256 * 512;             // 128*256
    int* cursor = (int*)(wd2 + 128 * 256);   // [N]
    int* bucket = cursor + N;                // [N*64]

    const dim3 blk(256);
    const dim3 blk1024(1024);
    const int nb128 = (N + 127) / 128;       // 391 row tiles
    const int cvtx = (N + 255) / 256;        // covers cursor slice (largest)

    // 1) weight converts + cursor zero
    cvt6_kernel<<<dim3(cvtx, 6), blk, 0, stream>>>(
        enc_w1, enc_w2, msg_w, dec_w1, dec_w2,
        w1, w2, wm, wd1, wd2, cursor,
        256 * 128 / 4, 256 * 256 / 4, 256 * 256 / 4,
        256 * 512 / 4, 128 * 256 / 4, N);

    // 2) bucket fill (scan-free CSR)
    fill_kernel<<<dim3((E + 255) / 256), blk, 0, stream>>>(
        ei, cursor, bucket, E, N);

    // 3) fused encoder (1024 thr, 128-row tiles): x -> h, m
    enc_fused<<<dim3(nb128), blk1024, 0, stream>>>(
        x, w1, enc_b1, w2, enc_b2, wm, msg_b, h, m, N);

    // 4) aggr = segment_sum(m[src], dst)  (one wave per node, unroll-8)
    gather_sum_kernel<<<dim3((N * 64 + 255) / 256), blk, 0, stream>>>(
        m, bucket, cursor, aggr, N);

    // 5) fused decoder (1024 thr, 128-row tiles): cat(aggr,h) -> out
    dec_fused<<<dim3(nb128), blk1024, 0, stream>>>(
        aggr, h, wd1, dec_b1, wd2, dec_b2, (float*)d_out, N);
}

// Round 8
// 235.183 us; speedup vs baseline: 1.1163x; 1.1163x over previous
//
#include <hip/hip_runtime.h>
#include <cmath>

// GNNCASimple: x:[N,128] -> enc MLP -> h:[N,256] -> (msg GEMM folded into dec)
// -> segment_sum over edges of h -> g:[N,256] -> dec(cat(g,h), Wc|Wd1h) -> out.
// N=50000, E=400000, D=128, H=256, steps=1.
//
// R13 best 234.6. R14-R20: seven structural variants of enc/dec (barriers,
// B-staging, LDS size, bank conflicts, persistence, 16-wave blocks) ALL
// neutral; every kernel pinned at ~1.0-1.2 TB/s effective HBM.
// MODEL (R21): total ~= SUM(bytes)/1.1TB/s (210MB -> ~235us). Only byte
// reduction moves total. Algebra: aggr = (SUM_src h[src])*Wm^T + deg*bm, so
//  (1) m deleted: gather sums h directly -> g (saves m write 25.6MB + fetch);
//  (2) Wc = Wd1a*Wm precomputed fp32 (wc_kernel), bc = Wd1a*bm; dec phase A
//      B = [Wc | Wd1h], bias += deg*bc (deg from cursor, staged in LDS);
//  (3) bucket int32 -> u16 (-6.4MB).
// enc = R19 persistent 2-phase (known-good) minus phase 3. dec = R16
// non-persistent form (known-good) with B-base switch + deg bias.

typedef __attribute__((ext_vector_type(8))) short  short8;   // 8 bf16 (4 VGPR)
typedef __attribute__((ext_vector_type(4))) float  f32x4;    // MFMA acc
typedef __attribute__((ext_vector_type(4))) unsigned short us4;

typedef unsigned short u16;
typedef unsigned int   u32;

static __device__ __forceinline__ u16 f2bf(float f) {
    u32 u = __float_as_uint(f);
    u = (u + 0x7FFFu + ((u >> 16) & 1u)) >> 16;   // round-to-nearest-even
    return (u16)u;
}
static __device__ __forceinline__ float bf2f(u16 h) {
    return __uint_as_float(((u32)h) << 16);
}

// async 16B global -> LDS; lds base wave-uniform (+ lane*16 implicit).
static __device__ __forceinline__ void g2l16(const void* g, void* l) {
    __builtin_amdgcn_global_load_lds(
        (const __attribute__((address_space(1))) u32*)g,
        (__attribute__((address_space(3))) u32*)l, 16, 0, 0);
}

// ---------------- fused encoder: x -> h (512 thr, persistent, 2 phases) ----
// Grid 256. Block loops tiles bid, bid+256, ... Per tile: 64 rows, 8 waves
// x 32 cols. hL[c][g][512] fragment-major. w1 (b1f) and w2 (bW) fragments +
// biases resident in VGPRs. Only global traffic: x reads + h writes.
__global__ __launch_bounds__(512, 2) void enc_fused(
    const float* __restrict__ x, const u16* __restrict__ w1,
    const float* __restrict__ b1, const u16* __restrict__ w2,
    const float* __restrict__ b2, u16* __restrict__ hout,
    const int N, const int ntiles)
{
    __shared__ u16 hL[8][4][512];   // 32KB; hL[4..7] doubles as x tile

    const int t    = threadIdx.x;
    const int wave = t >> 6;
    const int lane = t & 63;
    const int n    = lane & 15;
    const int q    = lane >> 4;
    const int wc   = wave * 32;

    // ---- tile-invariant resident fragments + biases ----
    short8 b1f[4][2];
#pragma unroll
    for (int c = 0; c < 4; c++)
#pragma unroll
        for (int j = 0; j < 2; j++)
            b1f[c][j] = *reinterpret_cast<const short8*>(
                w1 + (size_t)(wc + j * 16 + n) * 128 + c * 32 + q * 8);
    short8 bW[8][2];
#pragma unroll
    for (int c = 0; c < 8; c++)
#pragma unroll
        for (int j = 0; j < 2; j++)
            bW[c][j] = *reinterpret_cast<const short8*>(
                w2 + (size_t)(wc + j * 16 + n) * 256 + c * 32 + q * 8);
    const float bv1_0 = b1[wc + n], bv1_1 = b1[wc + 16 + n];
    const float bv2_0 = b2[wc + n], bv2_1 = b2[wc + 16 + n];

    // x-load mapping: thread covers rows xrow0+16k, col xcol (float4)
    const int xcol   = (t & 31) * 4;
    const int xrow0  = t >> 5;
    const int xchunk = xcol >> 5;
    const int xidx   = (((xcol >> 3) & 3) * 16 + xrow0) * 8 + (xcol & 7);

    float4 xr[4];
    int tile = blockIdx.x;
#pragma unroll
    for (int kk = 0; kk < 4; kk++) {
        const int gr = min(tile * 64 + xrow0 + kk * 16, N - 1);
        xr[kk] = *reinterpret_cast<const float4*>(x + (size_t)gr * 128 + xcol);
    }

    for (;;) {
        const int r0 = tile * 64;

        // ---- write x tile (bf16, fragment-major) into hL[4..7] ----
#pragma unroll
        for (int kk = 0; kk < 4; kk++) {
            us4 o = { f2bf(xr[kk].x), f2bf(xr[kk].y),
                      f2bf(xr[kk].z), f2bf(xr[kk].w) };
            *reinterpret_cast<us4*>(&hL[4 + xchunk][kk][xidx]) = o;
        }
        __syncthreads();   // x tile visible

        // prefetch next tile's x
        const int ntile = tile + 256;
        if (ntile < ntiles) {
#pragma unroll
            for (int kk = 0; kk < 4; kk++) {
                const int gr = min(ntile * 64 + xrow0 + kk * 16, N - 1);
                xr[kk] = *reinterpret_cast<const float4*>(
                    x + (size_t)gr * 128 + xcol);
            }
        }

        f32x4 acc[4][2];
#pragma unroll
        for (int i = 0; i < 4; i++)
#pragma unroll
            for (int j = 0; j < 2; j++) acc[i][j] = (f32x4)0.0f;

        // ---- phase 1: K=128 from x tile, B resident ----
#pragma unroll
        for (int c = 0; c < 4; c++) {
            short8 af[4];
#pragma unroll
            for (int i = 0; i < 4; i++)
                af[i] = *reinterpret_cast<const short8*>(
                    &hL[4 + c][i][lane * 8]);
#pragma unroll
            for (int i = 0; i < 4; i++)
#pragma unroll
                for (int j = 0; j < 2; j++)
                    acc[i][j] = __builtin_amdgcn_mfma_f32_16x16x32_bf16(
                        af[i], b1f[c][j], acc[i][j], 0, 0, 0);
        }
        __syncthreads();   // phase-1 reads done: hL[4..7] reusable

        {   // epilogue 1 -> hL chunk `wave`, fragment-major
            const int np = q * 4;
#pragma unroll
            for (int i = 0; i < 4; i++)
#pragma unroll
                for (int reg = 0; reg < 4; reg++) {
#pragma unroll
                    for (int j = 0; j < 2; j++) {
                        const float v = fmaxf(
                            acc[i][j][reg] + (j ? bv1_1 : bv1_0), 0.0f);
                        const int q2 = j * 2 + (n >> 3);
                        hL[wave][i][(q2 * 16 + np + reg) * 8 + (n & 7)] =
                            f2bf(v);
                    }
                }
        }
        __syncthreads();   // hL (h1) visible

        // ---- phase 2: K=256 from hL, B resident ----
#pragma unroll
        for (int i = 0; i < 4; i++)
#pragma unroll
            for (int j = 0; j < 2; j++) acc[i][j] = (f32x4)0.0f;
#pragma unroll
        for (int c = 0; c < 8; c++) {
            short8 af[4];
#pragma unroll
            for (int i = 0; i < 4; i++)
                af[i] = *reinterpret_cast<const short8*>(&hL[c][i][lane * 8]);
#pragma unroll
            for (int i = 0; i < 4; i++)
#pragma unroll
                for (int j = 0; j < 2; j++)
                    acc[i][j] = __builtin_amdgcn_mfma_f32_16x16x32_bf16(
                        af[i], bW[c][j], acc[i][j], 0, 0, 0);
        }

        {   // epilogue 2: h -> global only
#pragma unroll
            for (int i = 0; i < 4; i++)
#pragma unroll
                for (int reg = 0; reg < 4; reg++) {
                    const int row = r0 + i * 16 + q * 4 + reg;
                    if (row < N) {
                        hout[(size_t)row * 256 + wc + n] =
                            f2bf(fmaxf(acc[i][0][reg] + bv2_0, 0.0f));
                        hout[(size_t)row * 256 + wc + 16 + n] =
                            f2bf(fmaxf(acc[i][1][reg] + bv2_1, 0.0f));
                    }
                }
        }

        tile = ntile;
        if (tile >= ntiles) break;
        __syncthreads();   // phase-2 hL reads done before next x-tile write
    }
}

// ---------------- fused decoder: g,h -> out (512 threads, R16 form) --------
// Phase A: d = relu(cat(g,h)*[Wc|Wd1h]^T + bd1 + deg*bc), K=512. A staged
// per K-pair via g2l16 into dL[0..3] (fragment-major via pre-swizzled global
// source). B streams global->reg with base switch at chunk 8. Phase B:
// out = tanh(d Wd2^T + bd2), K=256 from dL.
__global__ __launch_bounds__(512, 4) void dec_fused(
    const u16* __restrict__ g, const u16* __restrict__ h,
    const u16* __restrict__ wcb, const u16* __restrict__ wd1,
    const float* __restrict__ bd1, const float* __restrict__ bc,
    const int* __restrict__ cursor,
    const u16* __restrict__ wd2, const float* __restrict__ bd2,
    float* __restrict__ out, const int N)
{
    __shared__ u16 dL[8][4][512];   // 32KB; dL[0..3] doubles as As[2][2]
    __shared__ float degL[64];

    const int t    = threadIdx.x;
    const int r0   = blockIdx.x * 64;
    const int wave = t >> 6;
    const int lane = t & 63;
    const int n    = lane & 15;
    const int q    = lane >> 4;
    const int wc   = wave * 32;

    const int w4   = wave & 3;
    const int sub  = wave >> 2;
    const int srow = min(r0 + w4 * 16 + (lane & 15), N - 1);
    const int kq8  = (lane >> 4) * 8;
    const u16* aptr = g + (size_t)srow * 256 + kq8;
    const u16* hptr = h + (size_t)srow * 256 + kq8;

#define DEC_STAGE(p, buf)                                                   \
    {                                                                       \
        const int c_  = 2 * (p) + sub;                                      \
        const int kc_ = c_ * 32;                                            \
        const u16* sp_ = (kc_ < 256) ? (aptr + kc_) : (hptr + (kc_ - 256)); \
        g2l16(sp_, &dL[(buf) * 2 + sub][w4][0]);                            \
    }

// B fragment address for chunk cc: cc<8 -> Wc (256-wide), else Wd1h part
#define BFRAG(cc, j)                                                        \
    ((cc) < 8                                                               \
     ? *reinterpret_cast<const short8*>(                                    \
           wcb + (size_t)(wc + (j) * 16 + n) * 256 + (cc) * 32 + q * 8)     \
     : *reinterpret_cast<const short8*>(                                    \
           wd1 + (size_t)(wc + (j) * 16 + n) * 512 + 256 +                  \
           ((cc) - 8) * 32 + q * 8))

    // deg staging (covered by the pair-0 barrier)
    if (t < 64) {
        const int cc = cursor[min(r0 + t, N - 1)];
        degL[t] = (float)(cc > 64 ? 64 : cc);
    }

    f32x4 acc[4][2];
#pragma unroll
    for (int i = 0; i < 4; i++)
#pragma unroll
        for (int j = 0; j < 2; j++) acc[i][j] = (f32x4)0.0f;

    DEC_STAGE(0, 0);
    // preload B steps 0..3 (all from Wc)
    short8 bp[4][2];
#pragma unroll
    for (int c = 0; c < 4; c++)
#pragma unroll
        for (int j = 0; j < 2; j++) bp[c][j] = BFRAG(c, j);
    __syncthreads();   // pair 0 staged; degL visible

    // ---- phase A: 8 K-pairs (K=512) ----
#pragma unroll
    for (int p = 0; p < 8; p++) {
        if (p < 7) DEC_STAGE(p + 1, (p + 1) & 1);   // overlap with compute
#pragma unroll
        for (int s = 0; s < 2; s++) {
            const int c = 2 * p + s;
            short8 af[4];
#pragma unroll
            for (int i = 0; i < 4; i++)
                af[i] = *reinterpret_cast<const short8*>(
                    &dL[(p & 1) * 2 + s][i][lane * 8]);
#pragma unroll
            for (int i = 0; i < 4; i++)
#pragma unroll
                for (int j = 0; j < 2; j++)
                    acc[i][j] = __builtin_amdgcn_mfma_f32_16x16x32_bf16(
                        af[i], bp[c & 3][j], acc[i][j], 0, 0, 0);
            if (c + 4 < 16) {
#pragma unroll
                for (int j = 0; j < 2; j++)
                    bp[c & 3][j] = BFRAG(c + 4, j);
            }
        }
        __syncthreads();   // next pair staged; reads of this pair done
    }
#undef DEC_STAGE
#undef BFRAG

    {   // epilogue A -> dL chunk `wave`, fragment-major; bias += deg*bc
        const float bv0 = bd1[wc + n];
        const float bv1 = bd1[wc + 16 + n];
        const float bc0 = bc[wc + n];
        const float bc1 = bc[wc + 16 + n];
        const int np = q * 4;
#pragma unroll
        for (int i = 0; i < 4; i++)
#pragma unroll
            for (int reg = 0; reg < 4; reg++) {
                const float dv = degL[i * 16 + q * 4 + reg];
#pragma unroll
                for (int j = 0; j < 2; j++) {
                    const float v = fmaxf(
                        acc[i][j][reg] + (j ? bv1 : bv0) +
                        dv * (j ? bc1 : bc0), 0.0f);
                    const int q2 = j * 2 + (n >> 3);
                    dL[wave][i][(q2 * 16 + np + reg) * 8 + (n & 7)] = f2bf(v);
                }
            }
    }

    // preload phase-B B (wd2: [128 out][256 K]); wave covers 16 out cols
    const int wc2 = wave * 16;
    short8 b2p[4];
#pragma unroll
    for (int c = 0; c < 4; c++)
        b2p[c] = *reinterpret_cast<const short8*>(
            wd2 + (size_t)(wc2 + n) * 256 + c * 32 + q * 8);
    __syncthreads();   // dL visible

    // ---- phase B: out 64x128, K=256 from dL ----
    f32x4 acc2[4];
#pragma unroll
    for (int i = 0; i < 4; i++) acc2[i] = (f32x4)0.0f;
#pragma unroll
    for (int c = 0; c < 8; c++) {
        short8 af[4], bf;
#pragma unroll
        for (int i = 0; i < 4; i++)
            af[i] = *reinterpret_cast<const short8*>(&dL[c][i][lane * 8]);
        bf = b2p[c & 3];
#pragma unroll
        for (int i = 0; i < 4; i++)
            acc2[i] = __builtin_amdgcn_mfma_f32_16x16x32_bf16(
                af[i], bf, acc2[i], 0, 0, 0);
        if (c < 4)
            b2p[c] = *reinterpret_cast<const short8*>(
                wd2 + (size_t)(wc2 + n) * 256 + (c + 4) * 32 + q * 8);
    }
    {
        const float bv = bd2[wc2 + n];
#pragma unroll
        for (int i = 0; i < 4; i++)
#pragma unroll
            for (int reg = 0; reg < 4; reg++) {
                const int row = r0 + i * 16 + q * 4 + reg;
                if (row < N)
                    out[(size_t)row * 128 + wc2 + n] = tanhf(acc2[i][reg] + bv);
            }
    }
}

// ---------------- Wc = Wd1a * Wm, bc = Wd1a * bm (fp32 accumulate) ---------
// Block o (0..255): thread j computes Wc[o][j] = sum_k wd1[o][k]*wm[k][j];
// LDS-reduce computes bc[o] = sum_k wd1[o][k]*bm[k].
__global__ __launch_bounds__(256) void wc_kernel(
    const float* __restrict__ wd1f, const float* __restrict__ wmf,
    const float* __restrict__ bmf, u16* __restrict__ wcb,
    float* __restrict__ bc)
{
    __shared__ float red[256];
    const int o = blockIdx.x;
    const int j = threadIdx.x;
    const float* wrow = wd1f + (size_t)o * 512;   // first 256 cols = Wd1a
    float acc = 0.0f;
    for (int k = 0; k < 256; k++)
        acc = fmaf(wrow[k], wmf[(size_t)k * 256 + j], acc);
    wcb[(size_t)o * 256 + j] = f2bf(acc);
    red[j] = wrow[j] * bmf[j];
    __syncthreads();
    for (int st = 128; st > 0; st >>= 1) {
        if (j < st) red[j] += red[j + st];
        __syncthreads();
    }
    if (j == 0) bc[o] = red[0];
}

// ---------------- weight converts + cursor zero (one dispatch) -------------
__global__ __launch_bounds__(256) void cvt5_kernel(
    const float* s0, const float* s1, const float* s2, const float* s3,
    u16* d0, u16* d1, u16* d2, u16* d3,
    int* __restrict__ zp,
    int n0, int n1, int n2, int n3, int nz)
{
    const int i = blockIdx.x * 256 + threadIdx.x;
    if (blockIdx.y == 4) {
        if (i < nz) zp[i] = 0;
        return;
    }
    const float* s; u16* d; int nq;
    switch (blockIdx.y) {
        case 0: s = s0; d = d0; nq = n0; break;
        case 1: s = s1; d = d1; nq = n1; break;
        case 2: s = s2; d = d2; nq = n2; break;
        default: s = s3; d = d3; nq = n3; break;
    }
    if (i < nq) {
        const float4 v = reinterpret_cast<const float4*>(s)[i];
        us4 o = { f2bf(v.x), f2bf(v.y), f2bf(v.z), f2bf(v.w) };
        reinterpret_cast<us4*>(d)[i] = o;
    }
}

// ---------------- scan-free bucket fill (u16 buckets) ----------------
// Fixed capacity 64 slots/node; deg ~ Poisson(8) => overflow prob ~1e-34.
__global__ __launch_bounds__(256) void fill_kernel(
    const int* __restrict__ ei, int* __restrict__ cursor,
    u16* __restrict__ bucket, const int E, const int Nn)
{
    const int e = blockIdx.x * 256 + threadIdx.x;
    if (e < E) {
        const int src = ei[e];
        const int dst = ei[(size_t)E + e];
        if ((unsigned)dst < (unsigned)Nn) {
            const int pos = atomicAdd(&cursor[dst], 1);
            if (pos < 64) bucket[(size_t)dst * 64 + pos] = (u16)src;
        }
    }
}

// ---------------- gather-sum over h (one wave per node, unroll-8) ----------
__global__ __launch_bounds__(256) void gather_sum_kernel(
    const u16* __restrict__ h, const u16* __restrict__ bucket,
    const int* __restrict__ cursor, u16* __restrict__ outg, const int Nn)
{
    const int wave = (int)((blockIdx.x * 256u + threadIdx.x) >> 6);
    const int lane = threadIdx.x & 63;
    if (wave >= Nn) return;
    const int cnt = min(cursor[wave], 64);
    const u16* bl = bucket + (size_t)wave * 64;
    float a0 = 0.f, a1 = 0.f, a2 = 0.f, a3 = 0.f;
    for (int base = 0; base < cnt; base += 8) {
        int sidx[8];
#pragma unroll
        for (int u = 0; u < 8; u++)
            sidx[u] = (base + u < cnt) ? (int)bl[base + u] : 0x10000;
        us4 v[8];
#pragma unroll
        for (int u = 0; u < 8; u++) {
            const int s = (sidx[u] < Nn) ? sidx[u] : 0;
            v[u] = *reinterpret_cast<const us4*>(&h[(size_t)s * 256 + lane * 4]);
        }
#pragma unroll
        for (int u = 0; u < 8; u++) {
            if (sidx[u] < Nn) {
                a0 += bf2f(v[u].x); a1 += bf2f(v[u].y);
                a2 += bf2f(v[u].z); a3 += bf2f(v[u].w);
            }
        }
    }
    us4 o = { f2bf(a0), f2bf(a1), f2bf(a2), f2bf(a3) };
    *reinterpret_cast<us4*>(&outg[(size_t)wave * 256 + lane * 4]) = o;
}

extern "C" void kernel_launch(void* const* d_in, const int* in_sizes, int n_in,
                              void* d_out, int out_size, void* d_ws, size_t ws_size,
                              hipStream_t stream)
{
    const float* x      = (const float*)d_in[0];
    const int*   ei     = (const int*)d_in[1];   // [2][E]
    const float* enc_w1 = (const float*)d_in[3];
    const float* enc_b1 = (const float*)d_in[4];
    const float* enc_w2 = (const float*)d_in[5];
    const float* enc_b2 = (const float*)d_in[6];
    const float* msg_w  = (const float*)d_in[7];
    const float* msg_b  = (const float*)d_in[8];
    const float* dec_w1 = (const float*)d_in[9];
    const float* dec_b1 = (const float*)d_in[10];
    const float* dec_w2 = (const float*)d_in[11];
    const float* dec_b2 = (const float*)d_in[12];

    const int N = 50000, D = 128, H = 256;
    const int E = in_sizes[1] / 2;

    // ws layout (u16 units unless noted)
    u16* h    = (u16*)d_ws;                  // [N,256]
    u16* g    = h   + (size_t)N * H;         // [N,256]  (gathered sum of h)
    u16* w1   = g   + (size_t)N * H;         // 256*128
    u16* w2   = w1 + 256 * 128;              // 256*256
    u16* wd1  = w2 + 256 * 256;              // 256*512 (full; dec uses cols 256+)
    u16* wd2  = wd1 + 256 * 512;             // 128*256
    u16* wcb  = wd2 + 128 * 256;             // 256*256 (Wc bf16)
    float* bc = (float*)(wcb + 256 * 256);   // [256] fp32
    int* cursor = (int*)(bc + 256);          // [N]
    u16* bucket = (u16*)(cursor + N);        // [N*64] u16

    const dim3 blk(256);
    const dim3 blk512(512);
    const int ntiles = (N + 63) / 64;        // 782 row tiles
    const int cvtx = (N + 255) / 256;        // covers cursor slice (largest)

    // 1) weight converts (w1, w2, wd1 full, wd2) + cursor zero
    cvt5_kernel<<<dim3(cvtx, 5), blk, 0, stream>>>(
        enc_w1, enc_w2, dec_w1, dec_w2,
        w1, w2, wd1, wd2, cursor,
        256 * 128 / 4, 256 * 256 / 4, 256 * 512 / 4, 128 * 256 / 4, N);

    // 2) Wc = Wd1a*Wm, bc = Wd1a*bm (fp32 accum, bf16 out)
    wc_kernel<<<dim3(256), blk, 0, stream>>>(dec_w1, msg_w, msg_b, wcb, bc);

    // 3) bucket fill (scan-free CSR, u16)
    fill_kernel<<<dim3((E + 255) / 256), blk, 0, stream>>>(
        ei, cursor, bucket, E, N);

    // 4) fused encoder (persistent, 256 blocks, 2 phases): x -> h
    enc_fused<<<dim3(256), blk512, 0, stream>>>(
        x, w1, enc_b1, w2, enc_b2, h, N, ntiles);

    // 5) g = segment_sum(h[src], dst)
    gather_sum_kernel<<<dim3((N * 64 + 255) / 256), blk, 0, stream>>>(
        h, bucket, cursor, g, N);

    // 6) fused decoder: cat(g,h)*[Wc|Wd1h]^T + deg*bc -> out
    dec_fused<<<dim3(ntiles), blk512, 0, stream>>>(
        g, h, wcb, wd1, dec_b1, bc, cursor, wd2, dec_b2, (float*)d_out, N);
}